// Round 6
// baseline (449.728 us; speedup 1.0000x reference)
//
#include <hip/hip_runtime.h>

#define N_NODES 50000
#define N_EDGES 800000
#define FEAT    128
#define NOUT    128
#define NBUCK   196                        // ceil(50000/256)
#define NTILE   ((N_EDGES + 2047) / 2048)  // 391 phase-A blocks
#define DBINS   64

typedef __attribute__((ext_vector_type(8))) short short8v;
typedef __attribute__((ext_vector_type(4))) float f32x4;
typedef __attribute__((ext_vector_type(2))) float f32x2;
typedef unsigned short ushort_t;
typedef unsigned char uchar_t;

#if defined(__has_builtin)
#if __has_builtin(__builtin_amdgcn_cvt_pk_f32_fp8) && __has_builtin(__builtin_amdgcn_cvt_pk_fp8_f32)
#define FP8_HW 1
#endif
#endif

static __device__ __forceinline__ unsigned short f2bf(float f) {
    union { float f; unsigned int u; } c; c.f = f;
    unsigned int u = c.u;
    return (unsigned short)((u + 0x7fffu + ((u >> 16) & 1u)) >> 16);
}
static __device__ __forceinline__ float bf_lo(unsigned int u) {
    return __uint_as_float(u << 16);
}
static __device__ __forceinline__ float bf_hi(unsigned int u) {
    return __uint_as_float(u & 0xffff0000u);
}

// ---- fp8 e4m3fn (OCP) helpers ----

static __device__ __forceinline__ unsigned int f2fp8_manual(float f) {
    unsigned int u = __float_as_uint(f);
    unsigned int s = (u >> 24) & 0x80u;
    unsigned int au = u & 0x7fffffffu;
    unsigned int q;
    if (au >= 0x43e00000u) {
        q = 0x7eu;
    } else if (au >= 0x3c800000u) {
        unsigned int e = (au >> 23) - 120u;
        unsigned int m = (au >> 20) & 7u;
        q = (e << 3) | m;
        unsigned int rem = au & 0xfffffu;
        q += (rem > 0x80000u) || ((rem == 0x80000u) && (q & 1u));
    } else {
        float af = __uint_as_float(au);
        q = (unsigned int)__float2int_rn(af * 512.0f);
    }
    return s | q;
}
static __device__ __forceinline__ float fp8_to_f32_manual(unsigned int b) {
    unsigned int s = (b & 0x80u) << 24;
    unsigned int q = b & 0x7fu;
    float r;
    if (q >= 8u) r = __uint_as_float((q << 20) + 0x3c000000u);
    else         r = (float)q * 0x1p-9f;
    return __uint_as_float(__float_as_uint(r) | s);
}

static __device__ __forceinline__ void fp8x4_dec(unsigned int u, float* o) {
#ifdef FP8_HW
    f32x2 lo = __builtin_amdgcn_cvt_pk_f32_fp8(u, false);
    f32x2 hi = __builtin_amdgcn_cvt_pk_f32_fp8(u, true);
    o[0] = lo[0]; o[1] = lo[1]; o[2] = hi[0]; o[3] = hi[1];
#else
    o[0] = fp8_to_f32_manual(u & 0xff);
    o[1] = fp8_to_f32_manual((u >> 8) & 0xff);
    o[2] = fp8_to_f32_manual((u >> 16) & 0xff);
    o[3] = fp8_to_f32_manual(u >> 24);
#endif
}
static __device__ __forceinline__ unsigned int fp8x4_enc(float a, float b, float c, float d) {
#ifdef FP8_HW
    int r = __builtin_amdgcn_cvt_pk_fp8_f32(a, b, 0, false);
    r = __builtin_amdgcn_cvt_pk_fp8_f32(c, d, r, true);
    return (unsigned int)r;
#else
    return f2fp8_manual(a) | (f2fp8_manual(b) << 8) |
           (f2fp8_manual(c) << 16) | (f2fp8_manual(d) << 24);
#endif
}

// ---------------- bucketed CSR build ----------------

__global__ void k_zero_int(int* __restrict__ p, int n) {
    int i = blockIdx.x * blockDim.x + threadIdx.x;
    if (i < n) p[i] = 0;
}

__global__ __launch_bounds__(256) void k_bhist(const int* __restrict__ rows,
                                               int* __restrict__ gcnt) {
    __shared__ int h[NBUCK];
    for (int i = threadIdx.x; i < NBUCK; i += 256) h[i] = 0;
    __syncthreads();
    const int base = blockIdx.x * 2048;
#pragma unroll
    for (int k = 0; k < 8; ++k) {
        int e = base + k * 256 + threadIdx.x;
        if (e < N_EDGES) atomicAdd(&h[rows[e] >> 8], 1);
    }
    __syncthreads();
    for (int i = threadIdx.x; i < NBUCK; i += 256)
        if (h[i]) atomicAdd(&gcnt[i], h[i]);
}

__global__ void k_bscan(const int* __restrict__ gcnt, int* __restrict__ bbase,
                        int* __restrict__ gfill) {
    if (threadIdx.x == 0 && blockIdx.x == 0) {
        int run = 0;
        for (int i = 0; i < NBUCK; ++i) {
            bbase[i] = run; gfill[i] = run; run += gcnt[i];
        }
        bbase[NBUCK] = run;
    }
}

__global__ __launch_bounds__(256) void k_bucketA(
    const int* __restrict__ rows, const int* __restrict__ cols,
    const float* __restrict__ vals, int* __restrict__ gfill,
    int2* __restrict__ bpairs)
{
    __shared__ int h[NBUCK];
    __shared__ int off[NBUCK];
    __shared__ int cb[NBUCK];
    for (int i = threadIdx.x; i < NBUCK; i += 256) { h[i] = 0; off[i] = 0; }
    __syncthreads();
    const int base = blockIdx.x * 2048;
    int enc[8];
#pragma unroll
    for (int k = 0; k < 8; ++k) {
        int e = base + k * 256 + threadIdx.x;
        enc[k] = -1;
        if (e < N_EDGES) {
            int r = rows[e];
            enc[k] = (r >> 8) | ((r & 255) << 16);
            atomicAdd(&h[r >> 8], 1);
        }
    }
    __syncthreads();
    for (int i = threadIdx.x; i < NBUCK; i += 256)
        cb[i] = h[i] ? atomicAdd(&gfill[i], h[i]) : 0;
    __syncthreads();
#pragma unroll
    for (int k = 0; k < 8; ++k) {
        int e = base + k * 256 + threadIdx.x;
        if (e >= N_EDGES) continue;
        int bk = enc[k] & 0xffff;
        int rowlo = enc[k] >> 16;
        int p = cb[bk] + atomicAdd(&off[bk], 1);
        int2 pr;
        pr.x = (rowlo << 16) | cols[e];
        pr.y = __float_as_int(vals[e]);
        bpairs[p] = pr;
    }
}

// Phase B: per-bucket row histogram + scan -> row_ptr + degree histogram,
// then local ordered scatter.
__global__ __launch_bounds__(256) void k_bucketB(
    const int* __restrict__ bbase, const int2* __restrict__ bpairs,
    int* __restrict__ row_ptr, int2* __restrict__ epairs,
    int* __restrict__ dcnt)
{
    __shared__ int hist[256];
    __shared__ int scan[256];
    __shared__ int fill[256];
    const int b = blockIdx.x;
    const int t = threadIdx.x;
    const int beg = bbase[b], end = bbase[b + 1];
    hist[t] = 0;
    __syncthreads();
    for (int j = beg + t; j < end; j += 256)
        atomicAdd(&hist[bpairs[j].x >> 16], 1);
    __syncthreads();
    int orig = hist[t];
    int val = orig;
    scan[t] = val;
    __syncthreads();
#pragma unroll
    for (int o = 1; o < 256; o <<= 1) {
        int y = (t >= o) ? scan[t - o] : 0;
        __syncthreads();
        val += y;
        scan[t] = val;
        __syncthreads();
    }
    const int rp = beg + (val - orig);
    const int gr = b * 256 + t;
    if (gr <= N_NODES) row_ptr[gr] = rp;
    if (gr < N_NODES) atomicAdd(&dcnt[min(orig, DBINS - 1)], 1);
    fill[t] = rp;
    __syncthreads();
    for (int j = beg + t; j < end; j += 256) {
        int2 pk = bpairs[j];
        int rowlo = pk.x >> 16;
        int p = atomicAdd(&fill[rowlo], 1);
        int2 pr;
        pr.x = pk.x & 0xffff;   // col (N=50000 < 65536)
        pr.y = pk.y;
        epairs[p] = pr;
    }
}

// degree-bin scan + row scatter -> rowperm (rows grouped by degree)
__global__ void k_dscan(const int* __restrict__ dcnt, int* __restrict__ dfill) {
    if (threadIdx.x == 0 && blockIdx.x == 0) {
        int run = 0;
        for (int i = 0; i < DBINS; ++i) { dfill[i] = run; run += dcnt[i]; }
    }
}

__global__ __launch_bounds__(256) void k_dscatter(const int* __restrict__ row_ptr,
                                                  int* __restrict__ dfill,
                                                  int* __restrict__ rowperm) {
    int i = blockIdx.x * 256 + threadIdx.x;
    if (i >= N_NODES) return;
    int deg = row_ptr[i + 1] - row_ptr[i];
    int bin = min(deg, DBINS - 1);
    int pos = atomicAdd(&dfill[bin], 1);
    rowperm[pos] = i;
}

// ---------------- x -> bf16 + fp8 copies ----------------

__global__ __launch_bounds__(256) void k_xconv(const float* __restrict__ x,
                                               ushort_t* __restrict__ xb,
                                               uchar_t* __restrict__ xf8) {
    int i = blockIdx.x * 256 + threadIdx.x;
    float4 f0 = *(const float4*)(x + (size_t)i * 8);
    float4 f1 = *(const float4*)(x + (size_t)i * 8 + 4);
    uint4 ob;
    ob.x = (unsigned int)f2bf(f0.x) | ((unsigned int)f2bf(f0.y) << 16);
    ob.y = (unsigned int)f2bf(f0.z) | ((unsigned int)f2bf(f0.w) << 16);
    ob.z = (unsigned int)f2bf(f1.x) | ((unsigned int)f2bf(f1.y) << 16);
    ob.w = (unsigned int)f2bf(f1.z) | ((unsigned int)f2bf(f1.w) << 16);
    *(uint4*)(xb + (size_t)i * 8) = ob;
    uint2 of;
    of.x = fp8x4_enc(f0.x, f0.y, f0.z, f0.w);
    of.y = fp8x4_enc(f1.x, f1.y, f1.z, f1.w);
    *(uint2*)(xf8 + (size_t)i * 8) = of;
}

// ---------------- SpMM: fp8 gather, fp32 accum, bf16(+fp8) store ----------------
// Degree-sorted rows via rowperm: 4 rows/wave with equal degree (no skew).
// Edge pairs -> two independent accumulator sets (2 outstanding gathers).

template <int MODE, int WF8>
__global__ __launch_bounds__(256) void k_spmm(
    const uchar_t* __restrict__ inf8, const int* __restrict__ row_ptr,
    const int* __restrict__ rowperm, const int2* __restrict__ epairs,
    const ushort_t* __restrict__ sub,
    ushort_t* __restrict__ outb, uchar_t* __restrict__ outf8)
{
    const int lane = threadIdx.x & 63;
    const int wid  = threadIdx.x >> 6;
    const int li   = lane & 15;
    const int slot = blockIdx.x * 16 + wid * 4 + (lane >> 4);
    const int r    = rowperm[slot];
    const int beg  = row_ptr[r];
    const int n    = row_ptr[r + 1] - beg;

    int nm = n;
    nm = max(nm, __shfl_xor(nm, 16));
    nm = max(nm, __shfl_xor(nm, 32));

    float a[8], b2[8];
#pragma unroll
    for (int k = 0; k < 8; ++k) { a[k] = 0.f; b2[k] = 0.f; }

    int j = 0;
    for (; j + 2 <= nm; j += 2) {
        bool act0 = (j < n), act1 = (j + 1 < n);
        int2 p0 = epairs[act0 ? beg + j : beg];
        int2 p1 = epairs[act1 ? beg + j + 1 : beg];
        float v0 = act0 ? __int_as_float(p0.y) : 0.f;
        float v1 = act1 ? __int_as_float(p1.y) : 0.f;
        uint2 u0 = *(const uint2*)(inf8 + ((size_t)p0.x << 7) + (li << 3));
        uint2 u1 = *(const uint2*)(inf8 + ((size_t)p1.x << 7) + (li << 3));
        float d0[8], d1[8];
        fp8x4_dec(u0.x, d0); fp8x4_dec(u0.y, d0 + 4);
        fp8x4_dec(u1.x, d1); fp8x4_dec(u1.y, d1 + 4);
#pragma unroll
        for (int k = 0; k < 8; ++k) {
            a[k]  = fmaf(v0, d0[k], a[k]);
            b2[k] = fmaf(v1, d1[k], b2[k]);
        }
    }
    if (j < nm) {
        bool act = (j < n);
        int2 p = epairs[act ? beg + j : beg];
        float v = act ? __int_as_float(p.y) : 0.f;
        uint2 u = *(const uint2*)(inf8 + ((size_t)p.x << 7) + (li << 3));
        float d[8];
        fp8x4_dec(u.x, d); fp8x4_dec(u.y, d + 4);
#pragma unroll
        for (int k = 0; k < 8; ++k) a[k] = fmaf(v, d[k], a[k]);
    }
#pragma unroll
    for (int k = 0; k < 8; ++k) a[k] += b2[k];

    if (MODE == 1) {
        uint4 su = *(const uint4*)(sub + (size_t)r * FEAT + li * 8);
        a[0] = 2.f * a[0] - bf_lo(su.x);
        a[1] = 2.f * a[1] - bf_hi(su.x);
        a[2] = 2.f * a[2] - bf_lo(su.y);
        a[3] = 2.f * a[3] - bf_hi(su.y);
        a[4] = 2.f * a[4] - bf_lo(su.z);
        a[5] = 2.f * a[5] - bf_hi(su.z);
        a[6] = 2.f * a[6] - bf_lo(su.w);
        a[7] = 2.f * a[7] - bf_hi(su.w);
    }

    uint4 ob;
    ob.x = (unsigned int)f2bf(a[0]) | ((unsigned int)f2bf(a[1]) << 16);
    ob.y = (unsigned int)f2bf(a[2]) | ((unsigned int)f2bf(a[3]) << 16);
    ob.z = (unsigned int)f2bf(a[4]) | ((unsigned int)f2bf(a[5]) << 16);
    ob.w = (unsigned int)f2bf(a[6]) | ((unsigned int)f2bf(a[7]) << 16);
    *(uint4*)(outb + (size_t)r * FEAT + li * 8) = ob;
    if (WF8) {
        uint2 of;
        of.x = fp8x4_enc(a[0], a[1], a[2], a[3]);
        of.y = fp8x4_enc(a[4], a[5], a[6], a[7]);
        *(uint2*)(outf8 + (size_t)r * FEAT + li * 8) = of;
    }
}

// ---------------- W prep: fp32 [512][128] -> bf16 fragment-ordered ----------------

__global__ void k_wprep(const float* __restrict__ W, ushort_t* __restrict__ wf) {
    int i = blockIdx.x * 256 + threadIdx.x;   // 8*16*64 = 8192
    if (i >= 8 * 16 * 64) return;
    int lane = i & 63;
    int kk = (i >> 6) & 15;
    int ct = i >> 10;
    int col = ct * 16 + (lane & 15);
    int k0 = kk * 32 + (lane >> 4) * 8;
    short8v o;
#pragma unroll
    for (int j = 0; j < 8; ++j)
        o[j] = (short)f2bf(W[(size_t)(k0 + j) * NOUT + col]);
    *(short8v*)(wf + (size_t)i * 8) = o;
}

// ---------------- Fused MFMA GEMM: out = [Xb|T1|T2|T3] @ W + b ----------------

__global__ __launch_bounds__(256) void k_mfma_gemm(
    const ushort_t* __restrict__ t0, const ushort_t* __restrict__ t1,
    const ushort_t* __restrict__ t2, const ushort_t* __restrict__ t3,
    const ushort_t* __restrict__ wfrag,
    const float* __restrict__ bias, float* __restrict__ out)
{
    const int lane = threadIdx.x & 63;
    const int wid  = threadIdx.x >> 6;
    const int m0   = blockIdx.x * 64 + wid * 16;
    const int cb   = blockIdx.y;
    const int arow = m0 + (lane & 15);
    const int kgrp = lane >> 4;

    f32x4 acc0 = {0.f, 0.f, 0.f, 0.f};
    f32x4 acc1 = {0.f, 0.f, 0.f, 0.f};
    f32x4 acc2 = {0.f, 0.f, 0.f, 0.f};
    f32x4 acc3 = {0.f, 0.f, 0.f, 0.f};

    const ushort_t* tp[4] = {t0, t1, t2, t3};
    const bool rowok = (arow < N_NODES);

#pragma unroll
    for (int kk = 0; kk < 16; ++kk) {
        const int term = kk >> 2;
        const ushort_t* ap = tp[term];
        short8v afrag;
        if (rowok) {
            afrag = *(const short8v*)(ap + (size_t)arow * FEAT + (kk & 3) * 32 + kgrp * 8);
        } else {
            afrag = (short8v)0;
        }
        const ushort_t* wb =
            wfrag + ((size_t)((cb * 4 + 0) * 16 + kk) * 64 + lane) * 8;
        short8v b0 = *(const short8v*)(wb);
        short8v b1 = *(const short8v*)(wb + 16 * 64 * 8);
        short8v b2 = *(const short8v*)(wb + 2 * 16 * 64 * 8);
        short8v b3 = *(const short8v*)(wb + 3 * 16 * 64 * 8);
        acc0 = __builtin_amdgcn_mfma_f32_16x16x32_bf16(afrag, b0, acc0, 0, 0, 0);
        acc1 = __builtin_amdgcn_mfma_f32_16x16x32_bf16(afrag, b1, acc1, 0, 0, 0);
        acc2 = __builtin_amdgcn_mfma_f32_16x16x32_bf16(afrag, b2, acc2, 0, 0, 0);
        acc3 = __builtin_amdgcn_mfma_f32_16x16x32_bf16(afrag, b3, acc3, 0, 0, 0);
    }

#pragma unroll
    for (int t = 0; t < 4; ++t) {
        f32x4 acc = (t == 0) ? acc0 : (t == 1) ? acc1 : (t == 2) ? acc2 : acc3;
        int col = cb * 64 + t * 16 + (lane & 15);
        float bv = bias[col];
#pragma unroll
        for (int i = 0; i < 4; ++i) {
            int row = m0 + kgrp * 4 + i;
            if (row < N_NODES) out[(size_t)row * NOUT + col] = acc[i] + bv;
        }
    }
}

// ---------------- launcher ----------------

extern "C" void kernel_launch(void* const* d_in, const int* in_sizes, int n_in,
                              void* d_out, int out_size, void* d_ws, size_t ws_size,
                              hipStream_t stream) {
    const float* x    = (const float*)d_in[0];
    const float* vals = (const float*)d_in[1];
    const float* W    = (const float*)d_in[2];
    const float* b    = (const float*)d_in[3];
    const int*   rows = (const int*)d_in[4];
    const int*   cols = (const int*)d_in[5];
    float* out = (float*)d_out;

    char* ws = (char*)d_ws;
    size_t off = 0;
    auto alloc = [&](size_t bytes) -> void* {
        void* p = ws + off;
        off = (off + bytes + 255) & ~(size_t)255;
        return p;
    };
    ushort_t* Xb    = (ushort_t*)alloc(sizeof(ushort_t) * (size_t)N_NODES * FEAT);
    ushort_t* T1b   = (ushort_t*)alloc(sizeof(ushort_t) * (size_t)N_NODES * FEAT);
    ushort_t* T2b   = (ushort_t*)alloc(sizeof(ushort_t) * (size_t)N_NODES * FEAT);
    ushort_t* T3b   = (ushort_t*)alloc(sizeof(ushort_t) * (size_t)N_NODES * FEAT);
    uchar_t*  Xf8   = (uchar_t*)alloc(sizeof(uchar_t) * (size_t)N_NODES * FEAT);
    uchar_t*  T1f8  = (uchar_t*)alloc(sizeof(uchar_t) * (size_t)N_NODES * FEAT);
    uchar_t*  T2f8  = (uchar_t*)alloc(sizeof(uchar_t) * (size_t)N_NODES * FEAT);
    int*   row_ptr  = (int*)alloc(sizeof(int) * (N_NODES + 1));
    int*   meta     = (int*)alloc(sizeof(int) * (NBUCK + DBINS));  // gcnt | dcnt
    int*   bbase    = (int*)alloc(sizeof(int) * (NBUCK + 1));
    int*   gfill    = (int*)alloc(sizeof(int) * NBUCK);
    int*   dfill    = (int*)alloc(sizeof(int) * DBINS);
    int*   rowperm  = (int*)alloc(sizeof(int) * N_NODES);
    int2*  bpairs   = (int2*)alloc(sizeof(int2) * (size_t)N_EDGES);
    int2*  epairs   = (int2*)alloc(sizeof(int2) * (size_t)N_EDGES);
    ushort_t* wfrag = (ushort_t*)alloc(sizeof(ushort_t) * 8 * 16 * 64 * 8);

    int* gcnt = meta;
    int* dcnt = meta + NBUCK;

    // bucketed CSR build + degree-sorted row permutation
    k_zero_int<<<2, 256, 0, stream>>>(meta, NBUCK + DBINS);
    k_bhist<<<NTILE, 256, 0, stream>>>(rows, gcnt);
    k_bscan<<<1, 64, 0, stream>>>(gcnt, bbase, gfill);
    k_bucketA<<<NTILE, 256, 0, stream>>>(rows, cols, vals, gfill, bpairs);
    k_bucketB<<<NBUCK, 256, 0, stream>>>(bbase, bpairs, row_ptr, epairs, dcnt);
    k_dscan<<<1, 64, 0, stream>>>(dcnt, dfill);
    k_dscatter<<<(N_NODES + 255) / 256, 256, 0, stream>>>(row_ptr, dfill, rowperm);

    // dense-side prep
    k_xconv<<<N_NODES * FEAT / 8 / 256, 256, 0, stream>>>(x, Xb, Xf8);
    k_wprep<<<32, 256, 0, stream>>>(W, wfrag);

    // Chebyshev recurrence: fp8 gather, fp32 accum, bf16(+fp8) store
    k_spmm<0, 1><<<N_NODES / 16, 256, 0, stream>>>(Xf8,  row_ptr, rowperm, epairs, nullptr, T1b, T1f8);
    k_spmm<1, 1><<<N_NODES / 16, 256, 0, stream>>>(T1f8, row_ptr, rowperm, epairs, Xb,      T2b, T2f8);
    k_spmm<1, 0><<<N_NODES / 16, 256, 0, stream>>>(T2f8, row_ptr, rowperm, epairs, T1b,     T3b, nullptr);

    // One fused MFMA GEMM: out = [Xb|T1|T2|T3] @ W + b
    dim3 grid((N_NODES + 63) / 64, 2);
    k_mfma_gemm<<<grid, 256, 0, stream>>>(Xb, T1b, T2b, T3b, wfrag, b, out);
}

// Round 7
// 176.705 us; speedup vs baseline: 2.5451x; 2.5451x over previous
//
#include <hip/hip_runtime.h>

#define N_NODES 50000
#define N_EDGES 800000
#define FEAT    128
#define NOUT    128
#define NBUCK   196                        // ceil(50000/256)
#define NTILE   ((N_EDGES + 2047) / 2048)  // 391 phase-A blocks
#define DBINS   64

typedef __attribute__((ext_vector_type(8))) short short8v;
typedef __attribute__((ext_vector_type(4))) float f32x4;
typedef __attribute__((ext_vector_type(2))) float f32x2;
typedef unsigned short ushort_t;
typedef unsigned char uchar_t;

#if defined(__has_builtin)
#if __has_builtin(__builtin_amdgcn_cvt_pk_f32_fp8) && __has_builtin(__builtin_amdgcn_cvt_pk_fp8_f32)
#define FP8_HW 1
#endif
#endif

static __device__ __forceinline__ unsigned short f2bf(float f) {
    union { float f; unsigned int u; } c; c.f = f;
    unsigned int u = c.u;
    return (unsigned short)((u + 0x7fffu + ((u >> 16) & 1u)) >> 16);
}
static __device__ __forceinline__ float bf_lo(unsigned int u) {
    return __uint_as_float(u << 16);
}
static __device__ __forceinline__ float bf_hi(unsigned int u) {
    return __uint_as_float(u & 0xffff0000u);
}

// ---- fp8 e4m3fn (OCP) helpers ----

static __device__ __forceinline__ unsigned int f2fp8_manual(float f) {
    unsigned int u = __float_as_uint(f);
    unsigned int s = (u >> 24) & 0x80u;
    unsigned int au = u & 0x7fffffffu;
    unsigned int q;
    if (au >= 0x43e00000u) {
        q = 0x7eu;
    } else if (au >= 0x3c800000u) {
        unsigned int e = (au >> 23) - 120u;
        unsigned int m = (au >> 20) & 7u;
        q = (e << 3) | m;
        unsigned int rem = au & 0xfffffu;
        q += (rem > 0x80000u) || ((rem == 0x80000u) && (q & 1u));
    } else {
        float af = __uint_as_float(au);
        q = (unsigned int)__float2int_rn(af * 512.0f);
    }
    return s | q;
}
static __device__ __forceinline__ float fp8_to_f32_manual(unsigned int b) {
    unsigned int s = (b & 0x80u) << 24;
    unsigned int q = b & 0x7fu;
    float r;
    if (q >= 8u) r = __uint_as_float((q << 20) + 0x3c000000u);
    else         r = (float)q * 0x1p-9f;
    return __uint_as_float(__float_as_uint(r) | s);
}

static __device__ __forceinline__ void fp8x4_dec(unsigned int u, float* o) {
#ifdef FP8_HW
    f32x2 lo = __builtin_amdgcn_cvt_pk_f32_fp8(u, false);
    f32x2 hi = __builtin_amdgcn_cvt_pk_f32_fp8(u, true);
    o[0] = lo[0]; o[1] = lo[1]; o[2] = hi[0]; o[3] = hi[1];
#else
    o[0] = fp8_to_f32_manual(u & 0xff);
    o[1] = fp8_to_f32_manual((u >> 8) & 0xff);
    o[2] = fp8_to_f32_manual((u >> 16) & 0xff);
    o[3] = fp8_to_f32_manual(u >> 24);
#endif
}
static __device__ __forceinline__ unsigned int fp8x4_enc(float a, float b, float c, float d) {
#ifdef FP8_HW
    int r = __builtin_amdgcn_cvt_pk_fp8_f32(a, b, 0, false);
    r = __builtin_amdgcn_cvt_pk_fp8_f32(c, d, r, true);
    return (unsigned int)r;
#else
    return f2fp8_manual(a) | (f2fp8_manual(b) << 8) |
           (f2fp8_manual(c) << 16) | (f2fp8_manual(d) << 24);
#endif
}

// ---------------- bucketed CSR build ----------------

__global__ void k_zero_int(int* __restrict__ p, int n) {
    int i = blockIdx.x * blockDim.x + threadIdx.x;
    if (i < n) p[i] = 0;
}

__global__ __launch_bounds__(256) void k_bhist(const int* __restrict__ rows,
                                               int* __restrict__ gcnt) {
    __shared__ int h[NBUCK];
    for (int i = threadIdx.x; i < NBUCK; i += 256) h[i] = 0;
    __syncthreads();
    const int base = blockIdx.x * 2048;
#pragma unroll
    for (int k = 0; k < 8; ++k) {
        int e = base + k * 256 + threadIdx.x;
        if (e < N_EDGES) atomicAdd(&h[rows[e] >> 8], 1);
    }
    __syncthreads();
    for (int i = threadIdx.x; i < NBUCK; i += 256)
        if (h[i]) atomicAdd(&gcnt[i], h[i]);
}

__global__ void k_bscan(const int* __restrict__ gcnt, int* __restrict__ bbase,
                        int* __restrict__ gfill) {
    if (threadIdx.x == 0 && blockIdx.x == 0) {
        int run = 0;
        for (int i = 0; i < NBUCK; ++i) {
            bbase[i] = run; gfill[i] = run; run += gcnt[i];
        }
        bbase[NBUCK] = run;
    }
}

__global__ __launch_bounds__(256) void k_bucketA(
    const int* __restrict__ rows, const int* __restrict__ cols,
    const float* __restrict__ vals, int* __restrict__ gfill,
    int2* __restrict__ bpairs)
{
    __shared__ int h[NBUCK];
    __shared__ int off[NBUCK];
    __shared__ int cb[NBUCK];
    for (int i = threadIdx.x; i < NBUCK; i += 256) { h[i] = 0; off[i] = 0; }
    __syncthreads();
    const int base = blockIdx.x * 2048;
    int enc[8];
#pragma unroll
    for (int k = 0; k < 8; ++k) {
        int e = base + k * 256 + threadIdx.x;
        enc[k] = -1;
        if (e < N_EDGES) {
            int r = rows[e];
            enc[k] = (r >> 8) | ((r & 255) << 16);
            atomicAdd(&h[r >> 8], 1);
        }
    }
    __syncthreads();
    for (int i = threadIdx.x; i < NBUCK; i += 256)
        cb[i] = h[i] ? atomicAdd(&gfill[i], h[i]) : 0;
    __syncthreads();
#pragma unroll
    for (int k = 0; k < 8; ++k) {
        int e = base + k * 256 + threadIdx.x;
        if (e >= N_EDGES) continue;
        int bk = enc[k] & 0xffff;
        int rowlo = enc[k] >> 16;
        int p = cb[bk] + atomicAdd(&off[bk], 1);
        int2 pr;
        pr.x = (rowlo << 16) | cols[e];
        pr.y = __float_as_int(vals[e]);
        bpairs[p] = pr;
    }
}

// Phase B: per-bucket row histogram + scan -> row_ptr + LDS-aggregated degree
// histogram, then local ordered scatter.
__global__ __launch_bounds__(256) void k_bucketB(
    const int* __restrict__ bbase, const int2* __restrict__ bpairs,
    int* __restrict__ row_ptr, int2* __restrict__ epairs,
    int* __restrict__ dcnt)
{
    __shared__ int hist[256];
    __shared__ int scan[256];
    __shared__ int fill[256];
    __shared__ int dh[DBINS];
    const int b = blockIdx.x;
    const int t = threadIdx.x;
    const int beg = bbase[b], end = bbase[b + 1];
    hist[t] = 0;
    if (t < DBINS) dh[t] = 0;
    __syncthreads();
    for (int j = beg + t; j < end; j += 256)
        atomicAdd(&hist[bpairs[j].x >> 16], 1);
    __syncthreads();
    int orig = hist[t];
    int val = orig;
    scan[t] = val;
    __syncthreads();
#pragma unroll
    for (int o = 1; o < 256; o <<= 1) {
        int y = (t >= o) ? scan[t - o] : 0;
        __syncthreads();
        val += y;
        scan[t] = val;
        __syncthreads();
    }
    const int rp = beg + (val - orig);
    const int gr = b * 256 + t;
    if (gr <= N_NODES) row_ptr[gr] = rp;
    if (gr < N_NODES) atomicAdd(&dh[min(orig, DBINS - 1)], 1);   // LDS, cheap
    fill[t] = rp;
    __syncthreads();
    if (t < DBINS && dh[t]) atomicAdd(&dcnt[t], dh[t]);          // few globals
    for (int j = beg + t; j < end; j += 256) {
        int2 pk = bpairs[j];
        int rowlo = pk.x >> 16;
        int p = atomicAdd(&fill[rowlo], 1);
        int2 pr;
        pr.x = pk.x & 0xffff;   // col (N=50000 < 65536)
        pr.y = pk.y;
        epairs[p] = pr;
    }
}

// degree-bin scan
__global__ void k_dscan(const int* __restrict__ dcnt, int* __restrict__ dfill) {
    if (threadIdx.x == 0 && blockIdx.x == 0) {
        int run = 0;
        for (int i = 0; i < DBINS; ++i) { dfill[i] = run; run += dcnt[i]; }
    }
}

// row scatter -> rowperm, LDS-aggregated chunk reservation (no hot global atomics)
__global__ __launch_bounds__(256) void k_dscatter(const int* __restrict__ row_ptr,
                                                  int* __restrict__ dfill,
                                                  int* __restrict__ rowperm) {
    __shared__ int h[DBINS];
    __shared__ int cb[DBINS];
    __shared__ int off[DBINS];
    const int t = threadIdx.x;
    if (t < DBINS) { h[t] = 0; off[t] = 0; }
    __syncthreads();
    const int i = blockIdx.x * 256 + t;
    int bin = -1;
    if (i < N_NODES) {
        int deg = row_ptr[i + 1] - row_ptr[i];
        bin = min(deg, DBINS - 1);
        atomicAdd(&h[bin], 1);
    }
    __syncthreads();
    if (t < DBINS) cb[t] = h[t] ? atomicAdd(&dfill[t], h[t]) : 0;
    __syncthreads();
    if (i < N_NODES) {
        int p = cb[bin] + atomicAdd(&off[bin], 1);
        rowperm[p] = i;
    }
}

// ---------------- x -> bf16 + fp8 copies ----------------

__global__ __launch_bounds__(256) void k_xconv(const float* __restrict__ x,
                                               ushort_t* __restrict__ xb,
                                               uchar_t* __restrict__ xf8) {
    int i = blockIdx.x * 256 + threadIdx.x;
    float4 f0 = *(const float4*)(x + (size_t)i * 8);
    float4 f1 = *(const float4*)(x + (size_t)i * 8 + 4);
    uint4 ob;
    ob.x = (unsigned int)f2bf(f0.x) | ((unsigned int)f2bf(f0.y) << 16);
    ob.y = (unsigned int)f2bf(f0.z) | ((unsigned int)f2bf(f0.w) << 16);
    ob.z = (unsigned int)f2bf(f1.x) | ((unsigned int)f2bf(f1.y) << 16);
    ob.w = (unsigned int)f2bf(f1.z) | ((unsigned int)f2bf(f1.w) << 16);
    *(uint4*)(xb + (size_t)i * 8) = ob;
    uint2 of;
    of.x = fp8x4_enc(f0.x, f0.y, f0.z, f0.w);
    of.y = fp8x4_enc(f1.x, f1.y, f1.z, f1.w);
    *(uint2*)(xf8 + (size_t)i * 8) = of;
}

// ---------------- SpMM: fp8 gather, fp32 accum, bf16(+fp8) store ----------------
// Degree-sorted rows via rowperm: 4 rows/wave with equal degree (no skew).
// Edge pairs -> two independent accumulator sets (2 outstanding gathers).

template <int MODE, int WF8>
__global__ __launch_bounds__(256) void k_spmm(
    const uchar_t* __restrict__ inf8, const int* __restrict__ row_ptr,
    const int* __restrict__ rowperm, const int2* __restrict__ epairs,
    const ushort_t* __restrict__ sub,
    ushort_t* __restrict__ outb, uchar_t* __restrict__ outf8)
{
    const int lane = threadIdx.x & 63;
    const int wid  = threadIdx.x >> 6;
    const int li   = lane & 15;
    const int slot = blockIdx.x * 16 + wid * 4 + (lane >> 4);
    const int r    = rowperm[slot];
    const int beg  = row_ptr[r];
    const int n    = row_ptr[r + 1] - beg;

    int nm = n;
    nm = max(nm, __shfl_xor(nm, 16));
    nm = max(nm, __shfl_xor(nm, 32));

    float a[8], b2[8];
#pragma unroll
    for (int k = 0; k < 8; ++k) { a[k] = 0.f; b2[k] = 0.f; }

    int j = 0;
    for (; j + 2 <= nm; j += 2) {
        bool act0 = (j < n), act1 = (j + 1 < n);
        int2 p0 = epairs[act0 ? beg + j : beg];
        int2 p1 = epairs[act1 ? beg + j + 1 : beg];
        float v0 = act0 ? __int_as_float(p0.y) : 0.f;
        float v1 = act1 ? __int_as_float(p1.y) : 0.f;
        uint2 u0 = *(const uint2*)(inf8 + ((size_t)p0.x << 7) + (li << 3));
        uint2 u1 = *(const uint2*)(inf8 + ((size_t)p1.x << 7) + (li << 3));
        float d0[8], d1[8];
        fp8x4_dec(u0.x, d0); fp8x4_dec(u0.y, d0 + 4);
        fp8x4_dec(u1.x, d1); fp8x4_dec(u1.y, d1 + 4);
#pragma unroll
        for (int k = 0; k < 8; ++k) {
            a[k]  = fmaf(v0, d0[k], a[k]);
            b2[k] = fmaf(v1, d1[k], b2[k]);
        }
    }
    if (j < nm) {
        bool act = (j < n);
        int2 p = epairs[act ? beg + j : beg];
        float v = act ? __int_as_float(p.y) : 0.f;
        uint2 u = *(const uint2*)(inf8 + ((size_t)p.x << 7) + (li << 3));
        float d[8];
        fp8x4_dec(u.x, d); fp8x4_dec(u.y, d + 4);
#pragma unroll
        for (int k = 0; k < 8; ++k) a[k] = fmaf(v, d[k], a[k]);
    }
#pragma unroll
    for (int k = 0; k < 8; ++k) a[k] += b2[k];

    if (MODE == 1) {
        uint4 su = *(const uint4*)(sub + (size_t)r * FEAT + li * 8);
        a[0] = 2.f * a[0] - bf_lo(su.x);
        a[1] = 2.f * a[1] - bf_hi(su.x);
        a[2] = 2.f * a[2] - bf_lo(su.y);
        a[3] = 2.f * a[3] - bf_hi(su.y);
        a[4] = 2.f * a[4] - bf_lo(su.z);
        a[5] = 2.f * a[5] - bf_hi(su.z);
        a[6] = 2.f * a[6] - bf_lo(su.w);
        a[7] = 2.f * a[7] - bf_hi(su.w);
    }

    uint4 ob;
    ob.x = (unsigned int)f2bf(a[0]) | ((unsigned int)f2bf(a[1]) << 16);
    ob.y = (unsigned int)f2bf(a[2]) | ((unsigned int)f2bf(a[3]) << 16);
    ob.z = (unsigned int)f2bf(a[4]) | ((unsigned int)f2bf(a[5]) << 16);
    ob.w = (unsigned int)f2bf(a[6]) | ((unsigned int)f2bf(a[7]) << 16);
    *(uint4*)(outb + (size_t)r * FEAT + li * 8) = ob;
    if (WF8) {
        uint2 of;
        of.x = fp8x4_enc(a[0], a[1], a[2], a[3]);
        of.y = fp8x4_enc(a[4], a[5], a[6], a[7]);
        *(uint2*)(outf8 + (size_t)r * FEAT + li * 8) = of;
    }
}

// ---------------- W prep: fp32 [512][128] -> bf16 fragment-ordered ----------------

__global__ void k_wprep(const float* __restrict__ W, ushort_t* __restrict__ wf) {
    int i = blockIdx.x * 256 + threadIdx.x;   // 8*16*64 = 8192
    if (i >= 8 * 16 * 64) return;
    int lane = i & 63;
    int kk = (i >> 6) & 15;
    int ct = i >> 10;
    int col = ct * 16 + (lane & 15);
    int k0 = kk * 32 + (lane >> 4) * 8;
    short8v o;
#pragma unroll
    for (int j = 0; j < 8; ++j)
        o[j] = (short)f2bf(W[(size_t)(k0 + j) * NOUT + col]);
    *(short8v*)(wf + (size_t)i * 8) = o;
}

// ---------------- Fused MFMA GEMM: out = [Xb|T1|T2|T3] @ W + b ----------------

__global__ __launch_bounds__(256) void k_mfma_gemm(
    const ushort_t* __restrict__ t0, const ushort_t* __restrict__ t1,
    const ushort_t* __restrict__ t2, const ushort_t* __restrict__ t3,
    const ushort_t* __restrict__ wfrag,
    const float* __restrict__ bias, float* __restrict__ out)
{
    const int lane = threadIdx.x & 63;
    const int wid  = threadIdx.x >> 6;
    const int m0   = blockIdx.x * 64 + wid * 16;
    const int cb   = blockIdx.y;
    const int arow = m0 + (lane & 15);
    const int kgrp = lane >> 4;

    f32x4 acc0 = {0.f, 0.f, 0.f, 0.f};
    f32x4 acc1 = {0.f, 0.f, 0.f, 0.f};
    f32x4 acc2 = {0.f, 0.f, 0.f, 0.f};
    f32x4 acc3 = {0.f, 0.f, 0.f, 0.f};

    const ushort_t* tp[4] = {t0, t1, t2, t3};
    const bool rowok = (arow < N_NODES);

#pragma unroll
    for (int kk = 0; kk < 16; ++kk) {
        const int term = kk >> 2;
        const ushort_t* ap = tp[term];
        short8v afrag;
        if (rowok) {
            afrag = *(const short8v*)(ap + (size_t)arow * FEAT + (kk & 3) * 32 + kgrp * 8);
        } else {
            afrag = (short8v)0;
        }
        const ushort_t* wb =
            wfrag + ((size_t)((cb * 4 + 0) * 16 + kk) * 64 + lane) * 8;
        short8v b0 = *(const short8v*)(wb);
        short8v b1 = *(const short8v*)(wb + 16 * 64 * 8);
        short8v b2 = *(const short8v*)(wb + 2 * 16 * 64 * 8);
        short8v b3 = *(const short8v*)(wb + 3 * 16 * 64 * 8);
        acc0 = __builtin_amdgcn_mfma_f32_16x16x32_bf16(afrag, b0, acc0, 0, 0, 0);
        acc1 = __builtin_amdgcn_mfma_f32_16x16x32_bf16(afrag, b1, acc1, 0, 0, 0);
        acc2 = __builtin_amdgcn_mfma_f32_16x16x32_bf16(afrag, b2, acc2, 0, 0, 0);
        acc3 = __builtin_amdgcn_mfma_f32_16x16x32_bf16(afrag, b3, acc3, 0, 0, 0);
    }

#pragma unroll
    for (int t = 0; t < 4; ++t) {
        f32x4 acc = (t == 0) ? acc0 : (t == 1) ? acc1 : (t == 2) ? acc2 : acc3;
        int col = cb * 64 + t * 16 + (lane & 15);
        float bv = bias[col];
#pragma unroll
        for (int i = 0; i < 4; ++i) {
            int row = m0 + kgrp * 4 + i;
            if (row < N_NODES) out[(size_t)row * NOUT + col] = acc[i] + bv;
        }
    }
}

// ---------------- launcher ----------------

extern "C" void kernel_launch(void* const* d_in, const int* in_sizes, int n_in,
                              void* d_out, int out_size, void* d_ws, size_t ws_size,
                              hipStream_t stream) {
    const float* x    = (const float*)d_in[0];
    const float* vals = (const float*)d_in[1];
    const float* W    = (const float*)d_in[2];
    const float* b    = (const float*)d_in[3];
    const int*   rows = (const int*)d_in[4];
    const int*   cols = (const int*)d_in[5];
    float* out = (float*)d_out;

    char* ws = (char*)d_ws;
    size_t off = 0;
    auto alloc = [&](size_t bytes) -> void* {
        void* p = ws + off;
        off = (off + bytes + 255) & ~(size_t)255;
        return p;
    };
    ushort_t* Xb    = (ushort_t*)alloc(sizeof(ushort_t) * (size_t)N_NODES * FEAT);
    ushort_t* T1b   = (ushort_t*)alloc(sizeof(ushort_t) * (size_t)N_NODES * FEAT);
    ushort_t* T2b   = (ushort_t*)alloc(sizeof(ushort_t) * (size_t)N_NODES * FEAT);
    ushort_t* T3b   = (ushort_t*)alloc(sizeof(ushort_t) * (size_t)N_NODES * FEAT);
    uchar_t*  Xf8   = (uchar_t*)alloc(sizeof(uchar_t) * (size_t)N_NODES * FEAT);
    uchar_t*  T1f8  = (uchar_t*)alloc(sizeof(uchar_t) * (size_t)N_NODES * FEAT);
    uchar_t*  T2f8  = (uchar_t*)alloc(sizeof(uchar_t) * (size_t)N_NODES * FEAT);
    int*   row_ptr  = (int*)alloc(sizeof(int) * (N_NODES + 1));
    int*   meta     = (int*)alloc(sizeof(int) * (NBUCK + DBINS));  // gcnt | dcnt
    int*   bbase    = (int*)alloc(sizeof(int) * (NBUCK + 1));
    int*   gfill    = (int*)alloc(sizeof(int) * NBUCK);
    int*   dfill    = (int*)alloc(sizeof(int) * DBINS);
    int*   rowperm  = (int*)alloc(sizeof(int) * N_NODES);
    int2*  bpairs   = (int2*)alloc(sizeof(int2) * (size_t)N_EDGES);
    int2*  epairs   = (int2*)alloc(sizeof(int2) * (size_t)N_EDGES);
    ushort_t* wfrag = (ushort_t*)alloc(sizeof(ushort_t) * 8 * 16 * 64 * 8);

    int* gcnt = meta;
    int* dcnt = meta + NBUCK;

    // bucketed CSR build + degree-sorted row permutation
    k_zero_int<<<2, 256, 0, stream>>>(meta, NBUCK + DBINS);
    k_bhist<<<NTILE, 256, 0, stream>>>(rows, gcnt);
    k_bscan<<<1, 64, 0, stream>>>(gcnt, bbase, gfill);
    k_bucketA<<<NTILE, 256, 0, stream>>>(rows, cols, vals, gfill, bpairs);
    k_bucketB<<<NBUCK, 256, 0, stream>>>(bbase, bpairs, row_ptr, epairs, dcnt);
    k_dscan<<<1, 64, 0, stream>>>(dcnt, dfill);
    k_dscatter<<<(N_NODES + 255) / 256, 256, 0, stream>>>(row_ptr, dfill, rowperm);

    // dense-side prep
    k_xconv<<<N_NODES * FEAT / 8 / 256, 256, 0, stream>>>(x, Xb, Xf8);
    k_wprep<<<32, 256, 0, stream>>>(W, wfrag);

    // Chebyshev recurrence: fp8 gather, fp32 accum, bf16(+fp8) store
    k_spmm<0, 1><<<N_NODES / 16, 256, 0, stream>>>(Xf8,  row_ptr, rowperm, epairs, nullptr, T1b, T1f8);
    k_spmm<1, 1><<<N_NODES / 16, 256, 0, stream>>>(T1f8, row_ptr, rowperm, epairs, Xb,      T2b, T2f8);
    k_spmm<1, 0><<<N_NODES / 16, 256, 0, stream>>>(T2f8, row_ptr, rowperm, epairs, T1b,     T3b, nullptr);

    // One fused MFMA GEMM: out = [Xb|T1|T2|T3] @ W + b
    dim3 grid((N_NODES + 63) / 64, 2);
    k_mfma_gemm<<<grid, 256, 0, stream>>>(Xb, T1b, T2b, T3b, wfrag, b, out);
}